// Round 1
// baseline (773.254 us; speedup 1.0000x reference)
//
#include <hip/hip_runtime.h>

#define NC   16      // channels
#define NP   48      // perception channels = 3*NC
#define NH   128     // hidden
#define HDIM 256
#define WDIM 256
#define HW   (HDIM*WDIM)

__global__ __launch_bounds__(256, 2) void nca_fused_kernel(
    const float* __restrict__ grid,
    const float* __restrict__ noise,
    const float* __restrict__ w1,
    const float* __restrict__ b1,
    const float* __restrict__ w2,
    const float* __restrict__ b2,
    float* __restrict__ out)
{
    __shared__ float s_w1[NH * NP];   // [o][c] 24 KB
    __shared__ float s_w2t[NH * NC];  // transposed: [o][j] 8 KB
    __shared__ float s_b1[NH];
    __shared__ float s_b2[NC];

    const int tid = threadIdx.x;

    // cooperative weight staging
    for (int i = tid; i < NH * NP; i += 256) s_w1[i] = w1[i];
    for (int i = tid; i < NH * NC; i += 256) {
        int j = i / NH;      // w2 is [NC][NH]
        int o = i % NH;
        s_w2t[o * NC + j] = w2[i];
    }
    if (tid < NH) s_b1[tid] = b1[tid];
    if (tid < NC) s_b2[tid] = b2[tid];
    __syncthreads();

    const int bIdx = blockIdx.x;          // 0..8191
    const int b = bIdx >> 8;              // batch
    const int y = bIdx & 255;             // row
    const int x = tid;                    // col

    const bool ym = (y > 0), yp = (y < HDIM - 1);
    const bool xm = (x > 0), xp = (x < WDIM - 1);
    const int xl = xm ? x - 1 : 0;        // clamped (value zeroed below)
    const int xr = xp ? x + 1 : x;

    const size_t base = (size_t)b * NC * HW + (size_t)y * WDIM;

    float p[NP];
    #pragma unroll
    for (int c = 0; c < NC; ++c) {
        const float* rowM = grid + base + (size_t)c * HW;
        const float* rowT = rowM + (ym ? -WDIM : 0);   // wave-uniform select
        const float* rowB = rowM + (yp ?  WDIM : 0);

        float tl0 = rowT[xl], tm0 = rowT[x], tr0 = rowT[xr];
        float ml0 = rowM[xl], mm  = rowM[x], mr0 = rowM[xr];
        float bl0 = rowB[xl], bm0 = rowB[x], br0 = rowB[xr];

        float tl = (ym && xm) ? tl0 : 0.f;
        float tm = ym         ? tm0 : 0.f;
        float tr = (ym && xp) ? tr0 : 0.f;
        float ml = xm         ? ml0 : 0.f;
        float mr = xp         ? mr0 : 0.f;
        float bl = (yp && xm) ? bl0 : 0.f;
        float bm = yp         ? bm0 : 0.f;
        float br = (yp && xp) ? br0 : 0.f;

        p[3*c]     = mm;
        // sobel_x as written: [[1,0,1],[2,0,-2],[1,0,-1]]/8 (cross-correlation)
        p[3*c + 1] = (tl + tr + 2.f*ml - 2.f*mr + bl - br) * 0.125f;
        // sobel_y: [[1,2,1],[0,0,0],[-1,-2,-1]]/8
        p[3*c + 2] = (tl + 2.f*tm + tr - bl - 2.f*bm - br) * 0.125f;
    }

    float upd[NC];
    #pragma unroll
    for (int j = 0; j < NC; ++j) upd[j] = s_b2[j];

    for (int o = 0; o < NH; ++o) {
        // h[o] = relu(b1[o] + w1[o,:] . p)  with 4-way ILP accumulators
        const float* wrow = &s_w1[o * NP];
        float a0 = s_b1[o], a1 = 0.f, a2 = 0.f, a3 = 0.f;
        #pragma unroll
        for (int c4 = 0; c4 < NP; c4 += 4) {
            float4 w = *(const float4*)&wrow[c4];
            a0 = fmaf(w.x, p[c4],     a0);
            a1 = fmaf(w.y, p[c4 + 1], a1);
            a2 = fmaf(w.z, p[c4 + 2], a2);
            a3 = fmaf(w.w, p[c4 + 3], a3);
        }
        float hv = fmaxf((a0 + a1) + (a2 + a3), 0.f);

        // fold into the 16 update accumulators
        const float4* w2r = (const float4*)&s_w2t[o * NC];
        #pragma unroll
        for (int j4 = 0; j4 < NC / 4; ++j4) {
            float4 w = w2r[j4];
            upd[4*j4]     = fmaf(w.x, hv, upd[4*j4]);
            upd[4*j4 + 1] = fmaf(w.y, hv, upd[4*j4 + 1]);
            upd[4*j4 + 2] = fmaf(w.z, hv, upd[4*j4 + 2]);
            upd[4*j4 + 3] = fmaf(w.w, hv, upd[4*j4 + 3]);
        }
    }

    // stochastic mask (broadcast over channels), residual, clip
    const float nz = noise[(size_t)b * HW + (size_t)y * WDIM + x];
    const float msk = (nz < 0.5f) ? 1.f : 0.f;

    #pragma unroll
    for (int j = 0; j < NC; ++j) {
        float v = p[3*j] + upd[j] * msk;           // p[3j] is the center (grid) value
        v = fminf(fmaxf(v, -2.f), 2.f);
        out[base + (size_t)j * HW + x] = v;
    }
}

extern "C" void kernel_launch(void* const* d_in, const int* in_sizes, int n_in,
                              void* d_out, int out_size, void* d_ws, size_t ws_size,
                              hipStream_t stream) {
    const float* grid  = (const float*)d_in[0];
    const float* noise = (const float*)d_in[1];
    const float* w1    = (const float*)d_in[2];
    const float* b1    = (const float*)d_in[3];
    const float* w2    = (const float*)d_in[4];
    const float* b2    = (const float*)d_in[5];
    float* out = (float*)d_out;

    dim3 g(32 * 256);   // one block per (batch, row)
    nca_fused_kernel<<<g, 256, 0, stream>>>(grid, noise, w1, b1, w2, b2, out);
}

// Round 2
// 449.147 us; speedup vs baseline: 1.7216x; 1.7216x over previous
//
#include <hip/hip_runtime.h>

#define NC   16      // channels
#define NP   48      // perception channels = 3*NC
#define NH   128     // hidden
#define HDIM 256
#define WDIM 256
#define HW   (HDIM*WDIM)

// LDS row strides (bf16 elements) chosen for 16B alignment + <=2-way banks
#define PSTR  56
#define W1STR 56
#define W2STR 136
#define HSTR  136

typedef __attribute__((ext_vector_type(8))) short short8;  // 8 bf16 = 1 MFMA operand
typedef __attribute__((ext_vector_type(4))) float f32x4;   // MFMA accumulator

__device__ __forceinline__ short f2bf(float f) {
    unsigned u = __float_as_uint(f);
    u += 0x7FFFu + ((u >> 16) & 1u);   // RNE
    return (short)(u >> 16);
}

__global__ __launch_bounds__(256, 3) void nca_mfma_kernel(
    const float* __restrict__ grid,
    const float* __restrict__ noise,
    const float* __restrict__ w1,
    const float* __restrict__ b1,
    const float* __restrict__ w2,
    const float* __restrict__ b2,
    float* __restrict__ out)
{
    // P: perception, [256 pixels][56] bf16 (+8 tail so q=3/t=1 reads stay in-bounds)
    __shared__ short sP[HDIM * PSTR + 8];
    // sW1/sW2 are dead after fragment setup; sH overlays them (saves 17.4 KB -> 3 blocks/CU)
    __shared__ union {
        struct { short w1[NH * W1STR + 8]; short w2[NC * W2STR]; } s;
        short H[4][16 * HSTR];
    } sU;

    const int tid = threadIdx.x;
    const int b = blockIdx.x >> 8;
    const int y = blockIdx.x & 255;

    // ---------- Phase 1: perception stencil (thread = pixel) ----------
    {
        const int x = tid;
        const bool ym = (y > 0), yp = (y < HDIM - 1);
        const bool xm = (x > 0), xp = (x < WDIM - 1);
        const int xl = xm ? x - 1 : 0;
        const int xr = xp ? x + 1 : x;
        const size_t base = (size_t)b * NC * HW + (size_t)y * WDIM;

        float p[NP];
        #pragma unroll
        for (int c = 0; c < NC; ++c) {
            const float* rowM = grid + base + (size_t)c * HW;
            const float* rowT = rowM + (ym ? -WDIM : 0);   // wave-uniform select
            const float* rowB = rowM + (yp ?  WDIM : 0);

            float tl0 = rowT[xl], tm0 = rowT[x], tr0 = rowT[xr];
            float ml0 = rowM[xl], mm  = rowM[x], mr0 = rowM[xr];
            float bl0 = rowB[xl], bm0 = rowB[x], br0 = rowB[xr];

            float tl = (ym && xm) ? tl0 : 0.f;
            float tm = ym         ? tm0 : 0.f;
            float tr = (ym && xp) ? tr0 : 0.f;
            float ml = xm         ? ml0 : 0.f;
            float mr = xp         ? mr0 : 0.f;
            float bl = (yp && xm) ? bl0 : 0.f;
            float bm = yp         ? bm0 : 0.f;
            float br = (yp && xp) ? br0 : 0.f;

            p[3*c]     = mm;
            p[3*c + 1] = (tl + tr + 2.f*ml - 2.f*mr + bl - br) * 0.125f;
            p[3*c + 2] = (tl + 2.f*tm + tr - bl - 2.f*bm - br) * 0.125f;
        }
        short* pw = &sP[x * PSTR];
        #pragma unroll
        for (int i = 0; i < 6; ++i) {
            short8 v;
            #pragma unroll
            for (int j = 0; j < 8; ++j) v[j] = f2bf(p[8*i + j]);
            *(short8*)&pw[8*i] = v;
        }
        short8 z = {};
        *(short8*)&pw[48] = z;   // zero k=48..55 pad
    }

    // ---------- Phase 2: stage weights to LDS as bf16 ----------
    {
        const int o = tid >> 1, half = tid & 1;   // 2 threads per w1 row
        const float* src = w1 + o * NP + half * 24;
        short* dst = &sU.s.w1[o * W1STR + half * 24];
        #pragma unroll
        for (int i = 0; i < 3; ++i) {
            short8 v;
            #pragma unroll
            for (int j = 0; j < 8; ++j) v[j] = f2bf(src[8*i + j]);
            *(short8*)&dst[8*i] = v;
        }
        if (half) { short8 z = {}; *(short8*)&sU.s.w1[o * W1STR + 48] = z; }
    }
    {
        const int j = tid >> 4, seg = tid & 15;   // w2: 16 rows x 16 segs of 8
        const float* src = w2 + j * NH + seg * 8;
        short8 v;
        #pragma unroll
        for (int k = 0; k < 8; ++k) v[k] = f2bf(src[k]);
        *(short8*)&sU.s.w2[j * W2STR + seg * 8] = v;
    }
    __syncthreads();

    // ---------- Phase 3: per-wave fragment setup (registers) ----------
    const int wv   = tid >> 6;
    const int lane = tid & 63;
    const int q    = lane >> 4;
    const int l15  = lane & 15;

    // GEMM1 B-frags: B[k=8q+j][n=l15] = w1[o=16n+l15][32t+8q+j]
    short8 w1f[8][2];
    #pragma unroll
    for (int n = 0; n < 8; ++n) {
        #pragma unroll
        for (int t = 0; t < 2; ++t) {
            const int kb = 32*t + 8*q;
            short8 v = *(const short8*)&sU.s.w1[(16*n + l15) * W1STR + kb];
            if (kb >= NP) { short8 z = {}; v = z; }   // K padded 48 -> 64
            w1f[n][t] = v;
        }
    }
    // GEMM2 B-frags in PERMUTED o-space: o' = a*8 + j' <-> o = j'*16 + a (a = 4t+q).
    // H is written with the same permutation, so the contraction is unchanged.
    short8 w2f[4];
    #pragma unroll
    for (int t = 0; t < 4; ++t) {
        short8 v;
        #pragma unroll
        for (int jj = 0; jj < 8; ++jj) v[jj] = sU.s.w2[l15 * W2STR + jj*16 + 4*t + q];
        w2f[t] = v;
    }
    float b1v[8];
    #pragma unroll
    for (int n = 0; n < 8; ++n) b1v[n] = b1[16*n + l15];
    const float b2v = b2[l15];

    __syncthreads();   // sW1/sW2 now dead; sH overlays them

    // ---------- Phase 4: MFMA MLP over this wave's 4 pixel-tiles ----------
    short* Hb = sU.H[wv];   // per-wave private, no barriers needed inside loop
    #pragma unroll
    for (int mt = 0; mt < 4; ++mt) {
        const int px0 = (wv * 4 + mt) * 16;
        const short* pr = &sP[(px0 + l15) * PSTR];
        const short8 a0 = *(const short8*)&pr[8*q];        // A[m=l15][k=8q+j], t=0
        const short8 a1 = *(const short8*)&pr[32 + 8*q];   // t=1 (k>=48 hits zero pad / x0 B)

        f32x4 acc[8];
        #pragma unroll
        for (int n = 0; n < 8; ++n) { f32x4 t4 = {b1v[n], b1v[n], b1v[n], b1v[n]}; acc[n] = t4; }
        #pragma unroll
        for (int n = 0; n < 8; ++n) {
            acc[n] = __builtin_amdgcn_mfma_f32_16x16x32_bf16(a0, w1f[n][0], acc[n], 0, 0, 0);
            acc[n] = __builtin_amdgcn_mfma_f32_16x16x32_bf16(a1, w1f[n][1], acc[n], 0, 0, 0);
        }
        // relu -> bf16 -> H' [m][o'=l15*8+n] (contiguous: one b128 per r)
        #pragma unroll
        for (int r = 0; r < 4; ++r) {
            short8 hv;
            #pragma unroll
            for (int n = 0; n < 8; ++n) hv[n] = f2bf(fmaxf(acc[n][r], 0.f));
            *(short8*)&Hb[(q*4 + r) * HSTR + l15 * 8] = hv;
        }
        // GEMM2: A[m=l15][k=o'=32t+8q+j] from H', B = w2f (same permutation)
        f32x4 acc2 = {b2v, b2v, b2v, b2v};
        #pragma unroll
        for (int t = 0; t < 4; ++t) {
            const short8 af = *(const short8*)&Hb[l15 * HSTR + 32*t + 8*q];
            acc2 = __builtin_amdgcn_mfma_f32_16x16x32_bf16(af, w2f[t], acc2, 0, 0, 0);
        }
        // Epilogue straight from C-layout: lane = (channel j=l15, pixels px0+4q..+3)
        const int px = px0 + 4*q;
        const size_t gi = (size_t)b * NC * HW + (size_t)l15 * HW + (size_t)y * WDIM + px;
        const float4 g  = *(const float4*)&grid[gi];                       // fp32 residual
        const float4 nz = *(const float4*)&noise[(size_t)b * HW + (size_t)y * WDIM + px];
        float4 o;
        o.x = fminf(fmaxf(g.x + acc2[0] * (nz.x < 0.5f ? 1.f : 0.f), -2.f), 2.f);
        o.y = fminf(fmaxf(g.y + acc2[1] * (nz.y < 0.5f ? 1.f : 0.f), -2.f), 2.f);
        o.z = fminf(fmaxf(g.z + acc2[2] * (nz.z < 0.5f ? 1.f : 0.f), -2.f), 2.f);
        o.w = fminf(fmaxf(g.w + acc2[3] * (nz.w < 0.5f ? 1.f : 0.f), -2.f), 2.f);
        *(float4*)&out[gi] = o;
    }
}

extern "C" void kernel_launch(void* const* d_in, const int* in_sizes, int n_in,
                              void* d_out, int out_size, void* d_ws, size_t ws_size,
                              hipStream_t stream) {
    const float* grid  = (const float*)d_in[0];
    const float* noise = (const float*)d_in[1];
    const float* w1    = (const float*)d_in[2];
    const float* b1    = (const float*)d_in[3];
    const float* w2    = (const float*)d_in[4];
    const float* b2    = (const float*)d_in[5];
    float* out = (float*)d_out;

    dim3 g(32 * 256);   // one block per (batch, row)
    nca_mfma_kernel<<<g, 256, 0, stream>>>(grid, noise, w1, b1, w2, b2, out);
}